// Round 5
// baseline (454.506 us; speedup 1.0000x reference)
//
#include <hip/hip_runtime.h>
#include <hip/hip_bf16.h>

// CDC conv: out = conv3x3(x,W,zero-pad) + b - 0.7 * laplacian(channel_sum(x), edge-pad)
// bf16 MFMA implicit GEMM (9 tap-GEMMs, K=Cin), fp32 stencil epilogue.
// Round 5: block = 512 thr / 8 waves, output tile 128co x 128w x 2 h-rows.
// xs = 4 input rows x 64ci half = 64KB LDS -> 2 blocks/CU = 4 waves/SIMD (50% occ).
// W fragments straight from global (L2-resident). XCD-aware block swizzle (T1).
// ws layout: [0,128MB) x_t bf16 [b][h][w][ci] (chunk-swizzled),
// [128MB,+288KB) W_packed [tap][kchunk:16][co:128][8ci] bf16 (linear),
// then s[b][h][w] f32 (8MB).

typedef __attribute__((ext_vector_type(8))) short short8;
typedef __attribute__((ext_vector_type(4))) float f32x4;

#define THETA 0.7f
#define XT_OFF   0
#define WP_OFF   134217728ull          // 32*128*128*128*2
#define S_OFF    (134217728ull + 294912ull)

__device__ __forceinline__ unsigned short f2b(float f) {
  unsigned u = __builtin_bit_cast(unsigned, f);
  u += 0x7FFFu + ((u >> 16) & 1u);     // RNE
  return (unsigned short)(u >> 16);
}

__device__ __forceinline__ void gload_lds16(const void* g, void* l) {
  __builtin_amdgcn_global_load_lds(
      (const __attribute__((address_space(1))) unsigned int*)g,
      (__attribute__((address_space(3))) unsigned int*)l, 16, 0, 0);
}

// ---- pack W[co][ci][3][3] f32 -> wp[tap][c:16][co:128][8] bf16 (linear)
__global__ void pack_w_kernel(const float* __restrict__ w, char* __restrict__ wp) {
  const int co = blockIdx.x, ci = threadIdx.x;
  const float* src = w + ((size_t)co * 128 + ci) * 9;
  const int c = ci >> 3, j = ci & 7;
  #pragma unroll
  for (int tap = 0; tap < 9; ++tap) {
    const unsigned short bv = f2b(src[tap]);
    *(unsigned short*)(wp + (((size_t)(tap * 16 + c) * 128 + co) * 16 + j * 2)) = bv;
  }
}

// ---- x[b][ci][h][w] f32 -> x_t[b][h][w][ci] bf16 (swizzled) + s[b][h][w] = sum_ci x
__global__ __launch_bounds__(256)
void transpose_sum_kernel(const float* __restrict__ x, char* __restrict__ xt,
                          float* __restrict__ s) {
  __shared__ float tile[128][129];
  __shared__ float s2[2][128];
  const int h = blockIdx.x, b = blockIdx.y;
  const int t = threadIdx.x;
  {
    const int ciq = t >> 5;              // 0..7
    const int wq = (t & 31) << 2;        // 0..124
    #pragma unroll
    for (int i = 0; i < 16; ++i) {
      const int ci = i * 8 + ciq;
      const float4 v = *(const float4*)(x + (((size_t)(b * 128 + ci) * 128 + h) * 128 + wq));
      tile[ci][wq] = v.x; tile[ci][wq + 1] = v.y;
      tile[ci][wq + 2] = v.z; tile[ci][wq + 3] = v.w;
    }
  }
  __syncthreads();
  {
    const int w = t & 127, p = t >> 7;
    float acc = 0.f;
    #pragma unroll 8
    for (int j = 0; j < 64; ++j) acc += tile[p * 64 + j][w];
    s2[p][w] = acc;
  }
  char* rowb = xt + (size_t)(b * 128 + h) * 32768;
  // 128 w * 16 chunks(16B) = 2048 chunks; 256 threads -> 8 iters
  #pragma unroll
  for (int i = 0; i < 8; ++i) {
    const int u = i * 256 + t;           // 0..2047 chunk id
    const int w = u >> 4, chunk = u & 15;
    const int ci0 = chunk * 8;
    short8 o;
    #pragma unroll
    for (int j = 0; j < 8; ++j) o[j] = (short)f2b(tile[ci0 + j][w]);
    *(short8*)(rowb + w * 256 + ((chunk ^ (w & 7)) * 16)) = o;
  }
  __syncthreads();
  if (t < 128) s[(size_t)(b * 128 + h) * 128 + t] = s2[0][t] + s2[1][t];
}

// ---- conv: 8 waves; block tile = 128co x 128w x 2 h-rows; W from global->regs
__global__ __launch_bounds__(512, 4)
void conv_mfma_kernel(const char* __restrict__ xt, const char* __restrict__ wp,
                      const float* __restrict__ bias, const float* __restrict__ s,
                      float* __restrict__ out) {
  __shared__ uint4 xs4[4 * 1024];   // 64KB: 4 input rows * 128w * 64ci bf16
  char* xs = (char*)xs4;

  // bijective XCD swizzle: 2048 blocks, 8 XCDs, 256 contiguous per XCD
  const int bid = blockIdx.x;
  const int sw = (bid & 7) * 256 + (bid >> 3);
  const int hp = sw & 63;           // h-pair
  const int b  = sw >> 6;           // batch
  const int h0 = hp * 2;

  const int t = threadIdx.x;
  const int lane = t & 63, wave = t >> 6;
  const int wm = (wave >> 2) & 1, wn = (wave >> 1) & 1, wh = wave & 1;
  const int l15 = lane & 15, lg = lane >> 4;
  const int h = h0 + wh;            // this wave's output row

  f32x4 acc[4][4];
  #pragma unroll
  for (int m = 0; m < 4; ++m)
    #pragma unroll
    for (int n = 0; n < 4; ++n)
      acc[m][n] = (f32x4){0.f, 0.f, 0.f, 0.f};

  auto stage_x = [&](int cih) {
    #pragma unroll
    for (int r = 0; r < 4; ++r) {  // input rows h0-1 .. h0+2, zero-pad OOB
      const int hh = h0 - 1 + r;
      if ((unsigned)hh < 128u) {
        const char* rb = xt + ((size_t)(b * 128 + hh) * 32768 + cih * 128);
        #pragma unroll
        for (int i = 0; i < 4; ++i) {
          const int u = i * 512 + t;   // 0..2047 chunk of the row-half
          gload_lds16(rb + (size_t)(u >> 3) * 256 + (u & 7) * 16,
                      xs + r * 16384 + u * 16);
        }
      } else {
        #pragma unroll
        for (int i = 0; i < 4; ++i) {
          const int u = i * 512 + t;
          *(uint4*)(xs + r * 16384 + u * 16) = make_uint4(0u, 0u, 0u, 0u);
        }
      }
    }
  };

  auto compute_half = [&](int khalf) {
    #pragma unroll
    for (int kh = 0; kh < 3; ++kh) {
      const char* xrow = xs + (wh + kh) * 16384;  // input row h-1+kh
      #pragma unroll
      for (int dxi = 0; dxi < 3; ++dxi) {
        const int tap = kh * 3 + dxi;
        const int dx = dxi - 1;
        // A-fragments direct from global (L2-resident), coalesced 256B runs
        const char* wb = wp + (size_t)(tap * 16 + khalf * 8) * 2048;
        short8 af[2][4];
        #pragma unroll
        for (int kk = 0; kk < 2; ++kk)
          #pragma unroll
          for (int m = 0; m < 4; ++m)
            af[kk][m] = *(const short8*)(wb + (kk * 4 + lg) * 2048 +
                                         (wm * 64 + m * 16 + l15) * 16);
        #pragma unroll
        for (int kk = 0; kk < 2; ++kk) {
          short8 bf[4];
          #pragma unroll
          for (int n = 0; n < 4; ++n) {
            const int wsrc = wn * 64 + n * 16 + l15 + dx;
            short8 v = {0, 0, 0, 0, 0, 0, 0, 0};
            if ((unsigned)wsrc < 128u) {
              const int phys = (kk * 4 + lg) ^ (wsrc & 7);
              v = *(const short8*)(xrow + wsrc * 128 + phys * 16);
            }
            bf[n] = v;
          }
          #pragma unroll
          for (int m = 0; m < 4; ++m)
            #pragma unroll
            for (int n = 0; n < 4; ++n)
              acc[m][n] = __builtin_amdgcn_mfma_f32_16x16x32_bf16(af[kk][m], bf[n], acc[m][n], 0, 0, 0);
        }
      }
    }
  };

  stage_x(0);
  __syncthreads();                 // xs half-0 ready
  compute_half(0);
  __syncthreads();                 // all waves done reading xs half-0
  stage_x(1);
  __syncthreads();                 // xs half-1 ready
  compute_half(1);

  // epilogue: per-thread fp32 stencil from s (L3-resident) + bias (L2)
  const float* sb = s + (size_t)b * 16384;
  float dif[4];
  #pragma unroll
  for (int n = 0; n < 4; ++n) {
    const int w = wn * 64 + n * 16 + l15;
    const float sc = sb[h * 128 + w];
    const float up = sb[(h > 0 ? h - 1 : 0) * 128 + w];
    const float dn = sb[(h < 127 ? h + 1 : 127) * 128 + w];
    const float lf = sb[h * 128 + (w > 0 ? w - 1 : 0)];
    const float rt = sb[h * 128 + (w < 127 ? w + 1 : 127)];
    dif[n] = up + dn + lf + rt - 4.0f * sc;
  }
  // C/D layout (verified m89): col=lane&15 (=pix), row=(lane>>4)*4+reg (=co)
  #pragma unroll
  for (int m = 0; m < 4; ++m) {
    #pragma unroll
    for (int r = 0; r < 4; ++r) {
      const int co = wm * 64 + m * 16 + lg * 4 + r;
      const float bv = bias[co];
      float* orow = out + ((size_t)(b * 128 + co) * 128 + h) * 128;
      #pragma unroll
      for (int n = 0; n < 4; ++n) {
        const int w = wn * 64 + n * 16 + l15;
        orow[w] = acc[m][n][r] + bv - THETA * dif[n];
      }
    }
  }
}

extern "C" void kernel_launch(void* const* d_in, const int* in_sizes, int n_in,
                              void* d_out, int out_size, void* d_ws, size_t ws_size,
                              hipStream_t stream) {
  const float* x = (const float*)d_in[0];
  const float* W = (const float*)d_in[1];
  const float* bias = (const float*)d_in[2];
  float* out = (float*)d_out;
  char* ws = (char*)d_ws;
  char* xt = ws + XT_OFF;
  char* wp = ws + WP_OFF;
  float* s = (float*)(ws + S_OFF);
  // needs ~142,901,248 bytes of ws
  pack_w_kernel<<<dim3(128), dim3(128), 0, stream>>>(W, wp);
  transpose_sum_kernel<<<dim3(128, 32), dim3(256), 0, stream>>>(x, xt, s);
  conv_mfma_kernel<<<dim3(2048), dim3(512), 0, stream>>>(xt, wp, bias, s, out);
}

// Round 6
// 261.148 us; speedup vs baseline: 1.7404x; 1.7404x over previous
//
#include <hip/hip_runtime.h>
#include <hip/hip_bf16.h>

// CDC conv: out = conv3x3(x,W,zero-pad) + b - 0.7 * laplacian(channel_sum(x), edge-pad)
// bf16 MFMA implicit GEMM (9 tap-GEMMs, K=Cin), fp32 stencil epilogue.
// Round 6: cut W-fragment bandwidth 6x. Block tile = 64co x 128w x 2h (4 waves:
// wh x wn); all waves read IDENTICAL W fragments (L1 broadcast); co-half moved
// to grid. LDS = 4 rows x 64ci = 64KB -> 2 blocks/CU. launch_bounds(256,2) so
// VGPR+AGPR (~148) never spills (round-5 lesson: (512,4) budget 128 -> spill).
// ws layout: [0,128MB) x_t bf16 [b][h][w][ci] (chunk-swizzled),
// [128MB,+288KB) W_packed [tap][kchunk:16][co:128][8ci] bf16 (linear),
// then s[b][h][w] f32 (8MB).

typedef __attribute__((ext_vector_type(8))) short short8;
typedef __attribute__((ext_vector_type(4))) float f32x4;

#define THETA 0.7f
#define XT_OFF   0
#define WP_OFF   134217728ull          // 32*128*128*128*2
#define S_OFF    (134217728ull + 294912ull)

__device__ __forceinline__ unsigned short f2b(float f) {
  unsigned u = __builtin_bit_cast(unsigned, f);
  u += 0x7FFFu + ((u >> 16) & 1u);     // RNE
  return (unsigned short)(u >> 16);
}

__device__ __forceinline__ void gload_lds16(const void* g, void* l) {
  __builtin_amdgcn_global_load_lds(
      (const __attribute__((address_space(1))) unsigned int*)g,
      (__attribute__((address_space(3))) unsigned int*)l, 16, 0, 0);
}

// ---- pack W[co][ci][3][3] f32 -> wp[tap][c:16][co:128][8] bf16 (linear)
__global__ void pack_w_kernel(const float* __restrict__ w, char* __restrict__ wp) {
  const int co = blockIdx.x, ci = threadIdx.x;
  const float* src = w + ((size_t)co * 128 + ci) * 9;
  const int c = ci >> 3, j = ci & 7;
  #pragma unroll
  for (int tap = 0; tap < 9; ++tap) {
    const unsigned short bv = f2b(src[tap]);
    *(unsigned short*)(wp + (((size_t)(tap * 16 + c) * 128 + co) * 16 + j * 2)) = bv;
  }
}

// ---- x[b][ci][h][w] f32 -> x_t[b][h][w][ci] bf16 (swizzled) + s[b][h][w] = sum_ci x
__global__ __launch_bounds__(256)
void transpose_sum_kernel(const float* __restrict__ x, char* __restrict__ xt,
                          float* __restrict__ s) {
  __shared__ float tile[128][129];
  __shared__ float s2[2][128];
  const int h = blockIdx.x, b = blockIdx.y;
  const int t = threadIdx.x;
  {
    const int ciq = t >> 5;              // 0..7
    const int wq = (t & 31) << 2;        // 0..124
    #pragma unroll
    for (int i = 0; i < 16; ++i) {
      const int ci = i * 8 + ciq;
      const float4 v = *(const float4*)(x + (((size_t)(b * 128 + ci) * 128 + h) * 128 + wq));
      tile[ci][wq] = v.x; tile[ci][wq + 1] = v.y;
      tile[ci][wq + 2] = v.z; tile[ci][wq + 3] = v.w;
    }
  }
  __syncthreads();
  {
    const int w = t & 127, p = t >> 7;
    float acc = 0.f;
    #pragma unroll 8
    for (int j = 0; j < 64; ++j) acc += tile[p * 64 + j][w];
    s2[p][w] = acc;
  }
  char* rowb = xt + (size_t)(b * 128 + h) * 32768;
  // 128 w * 16 chunks(16B) = 2048 chunks; 256 threads -> 8 iters
  #pragma unroll
  for (int i = 0; i < 8; ++i) {
    const int u = i * 256 + t;           // 0..2047 chunk id
    const int w = u >> 4, chunk = u & 15;
    const int ci0 = chunk * 8;
    short8 o;
    #pragma unroll
    for (int j = 0; j < 8; ++j) o[j] = (short)f2b(tile[ci0 + j][w]);
    *(short8*)(rowb + w * 256 + ((chunk ^ (w & 7)) * 16)) = o;
  }
  __syncthreads();
  if (t < 128) s[(size_t)(b * 128 + h) * 128 + t] = s2[0][t] + s2[1][t];
}

// ---- conv: 4 waves; block tile = 64co x 128w x 2h; W block-uniform from L1/L2
__global__ __launch_bounds__(256, 2)
void conv_mfma_kernel(const char* __restrict__ xt, const char* __restrict__ wp,
                      const float* __restrict__ bias, const float* __restrict__ s,
                      float* __restrict__ out) {
  __shared__ uint4 xs4[4 * 1024];   // 64KB: 4 input rows * 128w * 64ci bf16
  char* xs = (char*)xs4;

  // bijective XCD swizzle: 4096 blocks, 8 XCDs, 512 contiguous per XCD.
  // sw -> (b, hp, cohalf); both co-halves of an (b,hp) adjacent on one XCD.
  const int bid = blockIdx.x;
  const int sw = (bid & 7) * 512 + (bid >> 3);
  const int cohalf = sw & 1;
  const int hp = (sw >> 1) & 63;
  const int b  = sw >> 7;
  const int h0 = hp * 2;

  const int t = threadIdx.x;
  const int lane = t & 63, wave = t >> 6;
  const int wh = wave & 1, wn = (wave >> 1) & 1;
  const int l15 = lane & 15, lg = lane >> 4;
  const int h = h0 + wh;            // this wave's output row

  f32x4 acc[4][4];
  #pragma unroll
  for (int m = 0; m < 4; ++m)
    #pragma unroll
    for (int n = 0; n < 4; ++n)
      acc[m][n] = (f32x4){0.f, 0.f, 0.f, 0.f};

  auto stage_x = [&](int cih) {
    #pragma unroll
    for (int r = 0; r < 4; ++r) {  // input rows h0-1 .. h0+2, zero-pad OOB
      const int hh = h0 - 1 + r;
      if ((unsigned)hh < 128u) {
        const char* rb = xt + ((size_t)(b * 128 + hh) * 32768 + cih * 128);
        #pragma unroll
        for (int i = 0; i < 4; ++i) {
          const int u = i * 256 + t;   // 0..1023: 16KB row-half
          gload_lds16(rb + (size_t)(u >> 3) * 256 + (u & 7) * 16,
                      xs + r * 16384 + u * 16);
        }
      } else {
        #pragma unroll
        for (int i = 0; i < 4; ++i) {
          const int u = i * 256 + t;
          *(uint4*)(xs + r * 16384 + u * 16) = make_uint4(0u, 0u, 0u, 0u);
        }
      }
    }
  };

  auto compute_half = [&](int khalf) {
    #pragma unroll
    for (int kh = 0; kh < 3; ++kh) {
      const char* xrow = xs + (wh + kh) * 16384;  // input row h-1+kh
      #pragma unroll
      for (int dxi = 0; dxi < 3; ++dxi) {
        const int tap = kh * 3 + dxi;
        const int dx = dxi - 1;
        // A-fragments: identical for all 4 waves -> L1 broadcast
        const char* wb = wp + (size_t)(tap * 16 + khalf * 8) * 2048;
        short8 af[2][4];
        #pragma unroll
        for (int kk = 0; kk < 2; ++kk)
          #pragma unroll
          for (int m = 0; m < 4; ++m)
            af[kk][m] = *(const short8*)(wb + (kk * 4 + lg) * 2048 +
                                         (cohalf * 64 + m * 16 + l15) * 16);
        #pragma unroll
        for (int kk = 0; kk < 2; ++kk) {
          short8 bf[4];
          #pragma unroll
          for (int n = 0; n < 4; ++n) {
            const int wsrc = wn * 64 + n * 16 + l15 + dx;
            short8 v = {0, 0, 0, 0, 0, 0, 0, 0};
            if ((unsigned)wsrc < 128u) {
              const int phys = (kk * 4 + lg) ^ (wsrc & 7);
              v = *(const short8*)(xrow + wsrc * 128 + phys * 16);
            }
            bf[n] = v;
          }
          #pragma unroll
          for (int m = 0; m < 4; ++m)
            #pragma unroll
            for (int n = 0; n < 4; ++n)
              acc[m][n] = __builtin_amdgcn_mfma_f32_16x16x32_bf16(af[kk][m], bf[n], acc[m][n], 0, 0, 0);
        }
      }
    }
  };

  stage_x(0);
  __syncthreads();                 // xs half-0 ready
  compute_half(0);
  __syncthreads();                 // all waves done reading xs half-0
  stage_x(1);
  __syncthreads();                 // xs half-1 ready
  compute_half(1);

  // epilogue: per-thread fp32 stencil from s (L3-resident) + bias (L2)
  const float* sb = s + (size_t)b * 16384;
  float dif[4];
  #pragma unroll
  for (int n = 0; n < 4; ++n) {
    const int w = wn * 64 + n * 16 + l15;
    const float sc = sb[h * 128 + w];
    const float up = sb[(h > 0 ? h - 1 : 0) * 128 + w];
    const float dn = sb[(h < 127 ? h + 1 : 127) * 128 + w];
    const float lf = sb[h * 128 + (w > 0 ? w - 1 : 0)];
    const float rt = sb[h * 128 + (w < 127 ? w + 1 : 127)];
    dif[n] = up + dn + lf + rt - 4.0f * sc;
  }
  // C/D layout (verified m89): col=lane&15 (=pix), row=(lane>>4)*4+reg (=co)
  #pragma unroll
  for (int m = 0; m < 4; ++m) {
    #pragma unroll
    for (int r = 0; r < 4; ++r) {
      const int co = cohalf * 64 + m * 16 + lg * 4 + r;
      const float bv = bias[co];
      float* orow = out + ((size_t)(b * 128 + co) * 128 + h) * 128;
      #pragma unroll
      for (int n = 0; n < 4; ++n) {
        const int w = wn * 64 + n * 16 + l15;
        orow[w] = acc[m][n][r] + bv - THETA * dif[n];
      }
    }
  }
}

extern "C" void kernel_launch(void* const* d_in, const int* in_sizes, int n_in,
                              void* d_out, int out_size, void* d_ws, size_t ws_size,
                              hipStream_t stream) {
  const float* x = (const float*)d_in[0];
  const float* W = (const float*)d_in[1];
  const float* bias = (const float*)d_in[2];
  float* out = (float*)d_out;
  char* ws = (char*)d_ws;
  char* xt = ws + XT_OFF;
  char* wp = ws + WP_OFF;
  float* s = (float*)(ws + S_OFF);
  // needs ~142,901,248 bytes of ws
  pack_w_kernel<<<dim3(128), dim3(128), 0, stream>>>(W, wp);
  transpose_sum_kernel<<<dim3(128, 32), dim3(256), 0, stream>>>(x, xt, s);
  conv_mfma_kernel<<<dim3(4096), dim3(256), 0, stream>>>(xt, wp, bias, s, out);
}